// Round 3
// baseline (7794.759 us; speedup 1.0000x reference)
//
#include <hip/hip_runtime.h>
#include <hip/hip_bf16.h>
#include <math.h>

#define SEQ 1024
#define DM  1024
#define NH  16
#define HD  64
#define NL  4
#define FFD 4096
#define VOC 32000
#define EPS 1e-5f

typedef __hip_bfloat16 bf16;

// ---------------- embedding + sinusoidal positional encoding ----------------
__global__ __launch_bounds__(256) void embed_kernel(const int* __restrict__ x,
                                                    const float* __restrict__ emb,
                                                    float* __restrict__ h) {
    int s = blockIdx.x;
    int tok = x[s];
    const float c = -logf(10000.0f) / (float)DM;
    for (int d = threadIdx.x; d < DM; d += 256) {
        int j = d >> 1;
        float div = expf((float)(2 * j) * c);
        float ang = (float)s * div;
        float pe = (d & 1) ? cosf(ang) : sinf(ang);
        h[(size_t)s * DM + d] = emb[(size_t)tok * DM + d] + pe;
    }
}

// ---------------- layernorm (one block per row, D=1024) ----------------
__global__ __launch_bounds__(256) void ln_kernel(const float* __restrict__ in,
                                                 float* __restrict__ out,
                                                 const float* __restrict__ w,
                                                 const float* __restrict__ b) {
    __shared__ float red[256];
    int s = blockIdx.x;
    int tid = threadIdx.x;
    const float* row = in + (size_t)s * DM;

    float sum = 0.f;
    for (int d = tid; d < DM; d += 256) sum += row[d];
    red[tid] = sum; __syncthreads();
    for (int off = 128; off > 0; off >>= 1) {
        if (tid < off) red[tid] += red[tid + off];
        __syncthreads();
    }
    float mean = red[0] * (1.0f / DM);
    __syncthreads();

    float vs = 0.f;
    for (int d = tid; d < DM; d += 256) { float t = row[d] - mean; vs += t * t; }
    red[tid] = vs; __syncthreads();
    for (int off = 128; off > 0; off >>= 1) {
        if (tid < off) red[tid] += red[tid + off];
        __syncthreads();
    }
    float rstd = rsqrtf(red[0] * (1.0f / DM) + EPS);

    for (int d = tid; d < DM; d += 256)
        out[(size_t)s * DM + d] = (row[d] - mean) * rstd * w[d] + b[d];
}

// ---------------- generic tiled GEMM: C = op(A[f32] @ B[f32]) ----------------
// flags: 1 = add bias (f32 [N]); 2 = residual add into C (f32, in-place); 4 = relu
#define BM 64
#define BN 64
#define BK 16
#define F_BIAS 1
#define F_RES  2
#define F_RELU 4

__global__ __launch_bounds__(256) void gemm_kernel(const float* __restrict__ A,
                                                   const float* __restrict__ B,
                                                   const float* __restrict__ bias,
                                                   float* __restrict__ C,
                                                   int M, int N, int K, int flags) {
    __shared__ float As[BK][BM + 1];
    __shared__ float Bs[BK][BN + 1];
    int tid = threadIdx.x;
    int tx = tid & 15, ty = tid >> 4;
    int bm = blockIdx.y * BM, bn = blockIdx.x * BN;
    float acc[4][4] = {};

    for (int k0 = 0; k0 < K; k0 += BK) {
        // A tile: 64 rows x 16 k  (1024 elems, 4/thread)
        #pragma unroll
        for (int l = 0; l < 4; ++l) {
            int e = tid + l * 256;
            int r = e >> 4, c = e & 15;
            As[c][r] = A[(size_t)(bm + r) * K + k0 + c];
        }
        // B tile: 16 k x 64 cols
        #pragma unroll
        for (int l = 0; l < 4; ++l) {
            int e = tid + l * 256;
            int r = e >> 6, c = e & 63;
            Bs[r][c] = B[(size_t)(k0 + r) * N + bn + c];
        }
        __syncthreads();
        #pragma unroll
        for (int kk = 0; kk < BK; ++kk) {
            float a[4], bb[4];
            #pragma unroll
            for (int i = 0; i < 4; ++i) a[i] = As[kk][ty * 4 + i];
            #pragma unroll
            for (int j = 0; j < 4; ++j) bb[j] = Bs[kk][tx * 4 + j];
            #pragma unroll
            for (int i = 0; i < 4; ++i)
                #pragma unroll
                for (int j = 0; j < 4; ++j)
                    acc[i][j] = fmaf(a[i], bb[j], acc[i][j]);
        }
        __syncthreads();
    }

    #pragma unroll
    for (int i = 0; i < 4; ++i) {
        int m = bm + ty * 4 + i;
        #pragma unroll
        for (int j = 0; j < 4; ++j) {
            int n = bn + tx * 4 + j;
            float v = acc[i][j];
            if (flags & F_BIAS) v += bias[n];
            size_t idx = (size_t)m * N + n;
            if (flags & F_RES) v += C[idx];
            if (flags & F_RELU) v = fmaxf(v, 0.0f);
            C[idx] = v;
        }
    }
}

// ---------------- causal attention: one block per (query row, head) ----------------
__global__ __launch_bounds__(256) void attn_kernel(const float* __restrict__ q,
                                                   const float* __restrict__ k,
                                                   const float* __restrict__ v,
                                                   float* __restrict__ o) {
    __shared__ float qv[HD];
    __shared__ float sc[SEQ];
    __shared__ float red[256];
    int s = blockIdx.x;
    int hh = blockIdx.y;
    int tid = threadIdx.x;
    int base = hh * HD;

    if (tid < HD) qv[tid] = q[(size_t)s * DM + base + tid];
    __syncthreads();

    const float inv_scale = 0.125f;  // 1/sqrt(HD=64)
    float lmax = -1e30f;
    for (int kk = tid; kk <= s; kk += 256) {
        const float* kr = k + (size_t)kk * DM + base;
        float dot = 0.f;
        #pragma unroll
        for (int d = 0; d < HD; ++d) dot = fmaf(qv[d], kr[d], dot);
        dot *= inv_scale;
        sc[kk] = dot;
        lmax = fmaxf(lmax, dot);
    }
    red[tid] = lmax; __syncthreads();
    for (int off = 128; off > 0; off >>= 1) {
        if (tid < off) red[tid] = fmaxf(red[tid], red[tid + off]);
        __syncthreads();
    }
    float m = red[0];
    __syncthreads();

    float lsum = 0.f;
    for (int kk = tid; kk <= s; kk += 256) {
        float p = expf(sc[kk] - m);
        sc[kk] = p;
        lsum += p;
    }
    red[tid] = lsum; __syncthreads();
    for (int off = 128; off > 0; off >>= 1) {
        if (tid < off) red[tid] += red[tid + off];
        __syncthreads();
    }
    float inv_l = 1.0f / red[0];
    __syncthreads();

    // P @ V: 4 k-chunks x 64 dims
    int d = tid & 63, kc = tid >> 6;
    float acc = 0.f;
    for (int kk = kc; kk <= s; kk += 4)
        acc = fmaf(sc[kk], v[(size_t)kk * DM + base + d], acc);
    red[tid] = acc; __syncthreads();
    if (tid < HD) {
        float r2 = red[tid] + red[tid + 64] + red[tid + 128] + red[tid + 192];
        o[(size_t)s * DM + base + tid] = r2 * inv_l;
    }
}

extern "C" void kernel_launch(void* const* d_in, const int* in_sizes, int n_in,
                              void* d_out, int out_size, void* d_ws, size_t ws_size,
                              hipStream_t stream) {
    const int*   x       = (const int*)  d_in[0];
    const float* emb     = (const float*)d_in[1];
    const float* Wq      = (const float*)d_in[2];
    const float* Wk      = (const float*)d_in[3];
    const float* Wv      = (const float*)d_in[4];
    const float* Wo      = (const float*)d_in[5];
    const float* bo      = (const float*)d_in[6];
    const float* ln1_w   = (const float*)d_in[7];
    const float* ln1_b   = (const float*)d_in[8];
    const float* W1      = (const float*)d_in[9];
    const float* b1      = (const float*)d_in[10];
    const float* W2      = (const float*)d_in[11];
    const float* b2      = (const float*)d_in[12];
    const float* ln2_w   = (const float*)d_in[13];
    const float* ln2_b   = (const float*)d_in[14];
    const float* fn_w    = (const float*)d_in[15];
    const float* fn_b    = (const float*)d_in[16];
    const float* lm_head = (const float*)d_in[17];
    float* out = (float*)d_out;   // reference returns float32 logits

    // fp32 workspace: h, hn(also attn-out), q, k, v (1M floats each) + ff (4M floats) = 36 MB
    float* h  = (float*)d_ws;
    float* hn = h  + (size_t)SEQ * DM;
    float* qb = hn + (size_t)SEQ * DM;
    float* kb = qb + (size_t)SEQ * DM;
    float* vb = kb + (size_t)SEQ * DM;
    float* fb = vb + (size_t)SEQ * DM;
    float* ab = hn;  // attention output aliases hn (hn dead after V projection)

    embed_kernel<<<SEQ, 256, 0, stream>>>(x, emb, h);

    dim3 gD(DM / BN, SEQ / BM);    // 16 x 16
    dim3 gF(FFD / BN, SEQ / BM);   // 64 x 16
    dim3 gV(VOC / BN, SEQ / BM);   // 500 x 16

    for (int i = 0; i < NL; ++i) {
        ln_kernel<<<SEQ, 256, 0, stream>>>(h, hn, ln1_w + (size_t)i * DM, ln1_b + (size_t)i * DM);
        gemm_kernel<<<gD, 256, 0, stream>>>(hn, Wq + (size_t)i * DM * DM, nullptr, qb, SEQ, DM, DM, 0);
        gemm_kernel<<<gD, 256, 0, stream>>>(hn, Wk + (size_t)i * DM * DM, nullptr, kb, SEQ, DM, DM, 0);
        gemm_kernel<<<gD, 256, 0, stream>>>(hn, Wv + (size_t)i * DM * DM, nullptr, vb, SEQ, DM, DM, 0);
        attn_kernel<<<dim3(SEQ, NH), 256, 0, stream>>>(qb, kb, vb, ab);
        gemm_kernel<<<gD, 256, 0, stream>>>(ab, Wo + (size_t)i * DM * DM, bo + (size_t)i * DM, h,
                                            SEQ, DM, DM, F_BIAS | F_RES);
        ln_kernel<<<SEQ, 256, 0, stream>>>(h, hn, ln2_w + (size_t)i * DM, ln2_b + (size_t)i * DM);
        gemm_kernel<<<gF, 256, 0, stream>>>(hn, W1 + (size_t)i * DM * FFD, b1 + (size_t)i * FFD, fb,
                                            SEQ, FFD, DM, F_BIAS | F_RELU);
        gemm_kernel<<<gD, 256, 0, stream>>>(fb, W2 + (size_t)i * FFD * DM, b2 + (size_t)i * DM, h,
                                            SEQ, DM, FFD, F_BIAS | F_RES);
    }

    ln_kernel<<<SEQ, 256, 0, stream>>>(h, hn, fn_w, fn_b);
    gemm_kernel<<<gV, 256, 0, stream>>>(hn, lm_head, nullptr, out, SEQ, VOC, DM, 0);
}